// Round 2
// baseline (608.715 us; speedup 1.0000x reference)
//
#include <hip/hip_runtime.h>
#include <math.h>

#define Bsz 32
#define Tt  10
#define Dd  10
#define Uu  50
#define Pp  50
#define Ee  256

typedef __attribute__((ext_vector_type(8))) short bf16x8;   // MFMA A/B frag
typedef __attribute__((ext_vector_type(4))) float f32x4;    // MFMA C/D frag

#define STK 264   // sK / sXbf / sH row stride (halfwords): 256+8, 16B-aligned rows
#define STV 72    // sVt row stride (16B-aligned rows)
#define STS 72    // sS row stride

// LDS regions (bytes). ALL big tensors sequentially alias region A:
//  A [0,36864):      sK (scores B) -> sVt (PV B, V^T) -> sXbf (post-LN1) -> sH (post-relu)
//  B [36864,46080):  sS (softmax P, bf16)
//  C [46080,48128):  red f32[64][2][2] (LN1 partials) / red2 f32[64][4][2] (LN2 partials)
// Total 48,128 B -> 3 blocks/CU (3*48128 = 144,384 <= 163,840)
#define OFF_A 0
#define OFF_B 36864
#define OFF_C 46080
#define SMEM_TOT 48128

__device__ __forceinline__ unsigned short f2bf(float f) {      // RNE fp32->bf16
    unsigned u = __builtin_bit_cast(unsigned, f);
    u += 0x7fffu + ((u >> 16) & 1u);
    return (unsigned short)(u >> 16);
}
__device__ __forceinline__ float bf2f(unsigned short h) {
    unsigned u = ((unsigned)h) << 16;
    return __builtin_bit_cast(float, u);
}
// A/B fragment from LDS: lane q*16+l15 -> row r0+l15, cols c0+q*8..+7 (b128)
__device__ __forceinline__ bf16x8 ldfrag(const unsigned short* p, int stride, int r0, int c0, int lane) {
    return *(const bf16x8*)(p + (size_t)(r0 + (lane & 15)) * stride + c0 + ((lane >> 4) << 3));
}
// W fragment straight from global (bf16 ws if available, else fp32 + convert)
__device__ __forceinline__ bf16x8 wfrag(const unsigned short* wbf, const float* wf, int use_ws,
                                        int n, int k0, int lane) {
    const int row = n + (lane & 15);
    const int col = k0 + ((lane >> 4) << 3);
    if (use_ws) {
        return *(const bf16x8*)(wbf + (size_t)row * 256 + col);
    }
    const float4 a = *(const float4*)(wf + (size_t)row * 256 + col);
    const float4 b = *(const float4*)(wf + (size_t)row * 256 + col + 4);
    bf16x8 r;
    r[0] = (short)f2bf(a.x); r[1] = (short)f2bf(a.y); r[2] = (short)f2bf(a.z); r[3] = (short)f2bf(a.w);
    r[4] = (short)f2bf(b.x); r[5] = (short)f2bf(b.y); r[6] = (short)f2bf(b.z); r[7] = (short)f2bf(b.w);
    return r;
}

__global__ void convert_w_kernel(const float* __restrict__ W1, const float* __restrict__ W2,
                                 unsigned short* __restrict__ ws) {
    int i4 = (blockIdx.x * 256 + threadIdx.x) * 4;
    float4 a = *(const float4*)(W1 + i4);
    ushort4 oa; oa.x = f2bf(a.x); oa.y = f2bf(a.y); oa.z = f2bf(a.z); oa.w = f2bf(a.w);
    *(ushort4*)(ws + i4) = oa;
    float4 b = *(const float4*)(W2 + i4);
    ushort4 ob; ob.x = f2bf(b.x); ob.y = f2bf(b.y); ob.z = f2bf(b.z); ob.w = f2bf(b.w);
    *(ushort4*)(ws + 65536 + i4) = ob;
}

__global__ __launch_bounds__(512, 6) void fusion_kernel(
    const float* __restrict__ Q,  const float* __restrict__ K,
    const float* __restrict__ V,  const float* __restrict__ Msk,
    const float* __restrict__ W1, const float* __restrict__ b1,
    const float* __restrict__ W2, const float* __restrict__ b2,
    const float* __restrict__ ln1w, const float* __restrict__ ln1b,
    const float* __restrict__ ln2w, const float* __restrict__ ln2b,
    const unsigned short* __restrict__ wsbf, int use_ws,
    float* __restrict__ out)
{
    __shared__ __align__(16) unsigned char smem[SMEM_TOT];
    unsigned short* sK   = (unsigned short*)(smem + OFF_A);
    unsigned short* sVt  = (unsigned short*)(smem + OFF_A);   // after scores: sK dead
    unsigned short* sXbf = (unsigned short*)(smem + OFF_A);   // after PV: sVt dead
    unsigned short* sH   = (unsigned short*)(smem + OFF_A);   // after FFN1 reads: sXbf dead
    unsigned short* sS   = (unsigned short*)(smem + OFF_B);
    float*          red  = (float*)(smem + OFF_C);   // [u][half][2] (LN1)
    float*          red2 = (float*)(smem + OFF_C);   // [u][nq][2]   (LN2; red dead)

    const int tid  = threadIdx.x;
    const int lane = tid & 63;
    const int wave = tid >> 6;
    const int quad = lane >> 4;
    const int l15  = lane & 15;

    // XCD-chunked swizzle: hw block h -> XCD h%8 (round-robin). Map so each XCD
    // owns a contiguous btd chunk of 400 -> Q (d-neighbors) and K/V (t-neighbors,
    // stride 10) are fetched once per XCD instead of ~8x.
    const int btd = ((blockIdx.x & 7) * 400) + (blockIdx.x >> 3);
    const int b   = btd / (Tt * Dd);
    const int rem = btd % (Tt * Dd);
    const int t   = rem / Dd;
    const int d   = rem % Dd;

    const float* Qb = Q + ((size_t)(b * Tt + t) * Uu) * Ee;
    const float* Kb = K + ((size_t)(b * Dd + d) * Pp) * Ee;
    const float* Vb = V + ((size_t)(b * Dd + d) * Pp) * Ee;
    const float* Mb = Msk + ((size_t)((b * Tt + t) * Dd + d) * Uu) * Pp;
    float*       Ob = out + ((size_t)((b * Tt + t) * Dd + d) * Uu) * Ee;

    // ---- Stage K (all waves, coalesced) ----
    for (int i = tid; i < 3200; i += 512) {
        int r = i >> 6, c4 = (i & 63) << 2;
        float4 k = *(const float4*)(Kb + r * Ee + c4);
        ushort4 ok; ok.x = f2bf(k.x); ok.y = f2bf(k.y); ok.z = f2bf(k.z); ok.w = f2bf(k.w);
        *(ushort4*)(sK + r * STK + c4) = ok;
    }
    for (int i = tid; i < 924; i += 512) {     // zero rows 50..63 (14 x 66 ushort4)
        int r = 50 + i / 66, c = (i % 66) << 2;
        ushort4 z = {0, 0, 0, 0};
        *(ushort4*)(sK + r * STK + c) = z;
    }
    __syncthreads();   // B1: sK ready

    if (wave < 4) {
        // ---- Scores m-tile = wave: Q from global, K^T from LDS, softmax in registers ----
        const int mt = wave;
        int arow = mt * 16 + l15; if (arow > 49) arow = 49;   // clamp: garbage rows stay finite
        const float* qrow = Qb + (size_t)arow * Ee + (quad << 3);
        f32x4 acc[4];
        #pragma unroll
        for (int i = 0; i < 4; ++i) acc[i] = (f32x4){0.f, 0.f, 0.f, 0.f};
        #pragma unroll
        for (int k0 = 0; k0 < 256; k0 += 32) {
            float4 qa = *(const float4*)(qrow + k0);
            float4 qb = *(const float4*)(qrow + k0 + 4);
            bf16x8 a;
            a[0] = (short)f2bf(qa.x); a[1] = (short)f2bf(qa.y); a[2] = (short)f2bf(qa.z); a[3] = (short)f2bf(qa.w);
            a[4] = (short)f2bf(qb.x); a[5] = (short)f2bf(qb.y); a[6] = (short)f2bf(qb.z); a[7] = (short)f2bf(qb.w);
            #pragma unroll
            for (int nt = 0; nt < 4; ++nt) {
                bf16x8 bf = ldfrag(sK, STK, nt << 4, k0, lane);
                acc[nt] = __builtin_amdgcn_mfma_f32_16x16x32_bf16(a, bf, acc[nt], 0, 0, 0);
            }
        }
        // logits: scale (sqrt(256)+1e-8 == 16.0f in fp32) + mask; p>=50 -> -inf-ish
        float l[4][4];
        #pragma unroll
        for (int nt = 0; nt < 4; ++nt) {
            int p = (nt << 4) + l15;
            #pragma unroll
            for (int r = 0; r < 4; ++r) {
                int u = mt * 16 + (quad << 2) + r;
                float v = acc[nt][r] * 0.0625f;
                if (p < Pp) { if (u < Uu) v += Mb[u * Pp + p]; }
                else v = -1e30f;
                l[nt][r] = v;
            }
        }
        #pragma unroll
        for (int r = 0; r < 4; ++r) {
            float m = fmaxf(fmaxf(l[0][r], l[1][r]), fmaxf(l[2][r], l[3][r]));
            #pragma unroll
            for (int msk = 1; msk < 16; msk <<= 1) m = fmaxf(m, __shfl_xor(m, msk));
            float e0 = __expf(l[0][r] - m), e1 = __expf(l[1][r] - m);
            float e2 = __expf(l[2][r] - m), e3 = __expf(l[3][r] - m);
            float s = e0 + e1 + e2 + e3;
            #pragma unroll
            for (int msk = 1; msk < 16; msk <<= 1) s += __shfl_xor(s, msk);
            float inv = 1.0f / s;
            int u = mt * 16 + (quad << 2) + r;
            sS[u * STS +  0 + l15] = f2bf(e0 * inv);
            sS[u * STS + 16 + l15] = f2bf(e1 * inv);
            sS[u * STS + 32 + l15] = f2bf(e2 * inv);
            sS[u * STS + 48 + l15] = f2bf(e3 * inv);
        }
    }
    __syncthreads();   // B2: scores done, sK dead -> region A reusable

    // ---- Stage V^T into region A (all 512 threads; e per lane -> ~8-way write conflicts) ----
    for (int i = tid; i < 12800; i += 512) {
        int p = i >> 8, e = i & 255;
        sVt[e * STV + p] = f2bf(Vb[p * Ee + e]);
    }
    for (int i = tid; i < 3584; i += 512) {   // zero k-pad cols p=50..63
        int p = 50 + (i >> 8), e = i & 255;
        sVt[e * STV + p] = 0;
    }
    __syncthreads();   // B3: sVt ready

    // ---- PV: v_att = S.V (m-tile = w>>1, n-half = w&1) + Q residual + LN1 partials ----
    {
        const int mt = wave >> 1;
        const int nh = (wave & 1) << 7;
        f32x4 acc[8];
        #pragma unroll
        for (int i = 0; i < 8; ++i) acc[i] = (f32x4){0.f, 0.f, 0.f, 0.f};
        #pragma unroll
        for (int k0 = 0; k0 < 64; k0 += 32) {
            bf16x8 a = ldfrag(sS, STS, mt << 4, k0, lane);
            #pragma unroll
            for (int nt = 0; nt < 8; ++nt) {
                bf16x8 bf = ldfrag(sVt, STV, nh + (nt << 4), k0, lane);
                acc[nt] = __builtin_amdgcn_mfma_f32_16x16x32_bf16(a, bf, acc[nt], 0, 0, 0);
            }
        }
        float s1[4] = {0.f, 0.f, 0.f, 0.f}, s2[4] = {0.f, 0.f, 0.f, 0.f};
        #pragma unroll
        for (int nt = 0; nt < 8; ++nt) {
            int e = nh + (nt << 4) + l15;
            #pragma unroll
            for (int r = 0; r < 4; ++r) {
                int u = (mt << 4) + (quad << 2) + r;
                float x = 0.f;
                if (u < Uu) x = acc[nt][r] + Qb[(size_t)u * Ee + e];   // guard: no OOB Q read
                acc[nt][r] = x;
                s1[r] += x; s2[r] += x * x;
            }
        }
        #pragma unroll
        for (int msk = 1; msk < 16; msk <<= 1) {
            #pragma unroll
            for (int r = 0; r < 4; ++r) { s1[r] += __shfl_xor(s1[r], msk); s2[r] += __shfl_xor(s2[r], msk); }
        }
        if (l15 == 0) {
            #pragma unroll
            for (int r = 0; r < 4; ++r) {
                int u = (mt << 4) + (quad << 2) + r;
                red[u * 4 + (wave & 1) * 2 + 0] = s1[r];
                red[u * 4 + (wave & 1) * 2 + 1] = s2[r];
            }
        }
        __syncthreads();   // B4: red ready AND all PV reads of sVt done
        float mu[4], rstd[4];
        #pragma unroll
        for (int r = 0; r < 4; ++r) {
            int u = (mt << 4) + (quad << 2) + r;
            float sum = red[u * 4 + 0] + red[u * 4 + 2];
            float sq  = red[u * 4 + 1] + red[u * 4 + 3];
            mu[r] = sum * (1.0f / 256.0f);
            float var = sq * (1.0f / 256.0f) - mu[r] * mu[r];
            rstd[r] = rsqrtf(var + 1e-5f);
        }
        // write LN1 output into region A (sVt dead per B4)
        #pragma unroll
        for (int nt = 0; nt < 8; ++nt) {
            int e = nh + (nt << 4) + l15;
            float wv = ln1w[e], bv = ln1b[e];
            #pragma unroll
            for (int r = 0; r < 4; ++r) {
                int u = (mt << 4) + (quad << 2) + r;
                float o = (u < Uu) ? ((acc[nt][r] - mu[r]) * rstd[r] * wv + bv) : 0.f;
                sXbf[u * STK + e] = f2bf(o);
            }
        }
    }
    __syncthreads();   // B5: sXbf ready

    // ---- FFN1: H = relu(X.W1^T + b1); wave = (m-pair, n-quarter); W frags direct from L2 ----
    const int mp = wave >> 2;     // m-tiles {2mp, 2mp+1}
    const int nq = wave & 3;      // n-tiles 4nq..4nq+3
    unsigned resid[2][4][2];      // residual X at this wave's FFN2 output coords (packed bf16 pairs)
    {
        f32x4 acc2[2][4];
        #pragma unroll
        for (int mi = 0; mi < 2; ++mi)
            #pragma unroll
            for (int nt = 0; nt < 4; ++nt) acc2[mi][nt] = (f32x4){0.f, 0.f, 0.f, 0.f};
        float b1v[4];
        #pragma unroll
        for (int nt = 0; nt < 4; ++nt) b1v[nt] = b1[(nq << 6) + (nt << 4) + l15];
        #pragma unroll
        for (int k0 = 0; k0 < 256; k0 += 32) {
            bf16x8 a0 = ldfrag(sXbf, STK, (mp << 5),      k0, lane);
            bf16x8 a1 = ldfrag(sXbf, STK, (mp << 5) + 16, k0, lane);
            #pragma unroll
            for (int nt = 0; nt < 4; ++nt) {
                bf16x8 bf = wfrag(wsbf, W1, use_ws, (nq << 6) + (nt << 4), k0, lane);
                acc2[0][nt] = __builtin_amdgcn_mfma_f32_16x16x32_bf16(a0, bf, acc2[0][nt], 0, 0, 0);
                acc2[1][nt] = __builtin_amdgcn_mfma_f32_16x16x32_bf16(a1, bf, acc2[1][nt], 0, 0, 0);
            }
        }
        // capture residual X (32 bf16 -> 16 packed VGPRs) BEFORE sH overwrites region A
        #pragma unroll
        for (int mi = 0; mi < 2; ++mi)
            #pragma unroll
            for (int nt = 0; nt < 4; ++nt) {
                int j = (nq << 6) + (nt << 4) + l15;
                #pragma unroll
                for (int rp = 0; rp < 2; ++rp) {
                    int u0 = (mp << 5) + (mi << 4) + (quad << 2) + rp * 2;
                    unsigned lo = sXbf[(size_t)u0 * STK + j];
                    unsigned hi = sXbf[(size_t)(u0 + 1) * STK + j];
                    resid[mi][nt][rp] = lo | (hi << 16);
                }
            }
        __syncthreads();   // B6: all sXbf reads (A-frags + residual) done
        #pragma unroll
        for (int mi = 0; mi < 2; ++mi)
            #pragma unroll
            for (int nt = 0; nt < 4; ++nt) {
                int j = (nq << 6) + (nt << 4) + l15;
                #pragma unroll
                for (int r = 0; r < 4; ++r) {
                    int u = (mp << 5) + (mi << 4) + (quad << 2) + r;
                    sH[u * STK + j] = f2bf(fmaxf(acc2[mi][nt][r] + b1v[nt], 0.f));
                }
            }
    }
    __syncthreads();   // B7: sH ready

    // ---- FFN2: Y = H.W2^T + b2 + X(regs); LN2; store ----
    {
        f32x4 acc2[2][4];
        #pragma unroll
        for (int mi = 0; mi < 2; ++mi)
            #pragma unroll
            for (int nt = 0; nt < 4; ++nt) acc2[mi][nt] = (f32x4){0.f, 0.f, 0.f, 0.f};
        float b2v[4], w2l[4], b2l[4];
        #pragma unroll
        for (int nt = 0; nt < 4; ++nt) {
            int j = (nq << 6) + (nt << 4) + l15;
            b2v[nt] = b2[j]; w2l[nt] = ln2w[j]; b2l[nt] = ln2b[j];
        }
        #pragma unroll
        for (int k0 = 0; k0 < 256; k0 += 32) {
            bf16x8 a0 = ldfrag(sH, STK, (mp << 5),      k0, lane);
            bf16x8 a1 = ldfrag(sH, STK, (mp << 5) + 16, k0, lane);
            #pragma unroll
            for (int nt = 0; nt < 4; ++nt) {
                bf16x8 bf = wfrag(wsbf + 65536, W2, use_ws, (nq << 6) + (nt << 4), k0, lane);
                acc2[0][nt] = __builtin_amdgcn_mfma_f32_16x16x32_bf16(a0, bf, acc2[0][nt], 0, 0, 0);
                acc2[1][nt] = __builtin_amdgcn_mfma_f32_16x16x32_bf16(a1, bf, acc2[1][nt], 0, 0, 0);
            }
        }
        // y = ffn2 + b2 + residual X(regs); per-row partial sums over this wave's 64 cols
        float s1[2][4], s2[2][4];
        #pragma unroll
        for (int mi = 0; mi < 2; ++mi)
            #pragma unroll
            for (int r = 0; r < 4; ++r) { s1[mi][r] = 0.f; s2[mi][r] = 0.f; }
        #pragma unroll
        for (int mi = 0; mi < 2; ++mi)
            #pragma unroll
            for (int nt = 0; nt < 4; ++nt) {
                #pragma unroll
                for (int r = 0; r < 4; ++r) {
                    unsigned pk = resid[mi][nt][r >> 1];
                    unsigned short rb = (r & 1) ? (unsigned short)(pk >> 16) : (unsigned short)(pk & 0xffffu);
                    float y = acc2[mi][nt][r] + b2v[nt] + bf2f(rb);
                    acc2[mi][nt][r] = y;
                    s1[mi][r] += y; s2[mi][r] += y * y;
                }
            }
        #pragma unroll
        for (int msk = 1; msk < 16; msk <<= 1)
            #pragma unroll
            for (int mi = 0; mi < 2; ++mi)
                #pragma unroll
                for (int r = 0; r < 4; ++r) {
                    s1[mi][r] += __shfl_xor(s1[mi][r], msk);
                    s2[mi][r] += __shfl_xor(s2[mi][r], msk);
                }
        if (l15 == 0) {
            #pragma unroll
            for (int mi = 0; mi < 2; ++mi)
                #pragma unroll
                for (int r = 0; r < 4; ++r) {
                    int u = (mp << 5) + (mi << 4) + (quad << 2) + r;
                    red2[u * 8 + nq * 2 + 0] = s1[mi][r];
                    red2[u * 8 + nq * 2 + 1] = s2[mi][r];
                }
        }
        __syncthreads();   // B8: red2 ready
        #pragma unroll
        for (int mi = 0; mi < 2; ++mi)
            #pragma unroll
            for (int r = 0; r < 4; ++r) {
                int u = (mp << 5) + (mi << 4) + (quad << 2) + r;
                if (u < Uu) {
                    float sum = red2[u * 8 + 0] + red2[u * 8 + 2] + red2[u * 8 + 4] + red2[u * 8 + 6];
                    float sq  = red2[u * 8 + 1] + red2[u * 8 + 3] + red2[u * 8 + 5] + red2[u * 8 + 7];
                    float mu = sum * (1.0f / 256.0f);
                    float var = sq * (1.0f / 256.0f) - mu * mu;
                    float rstd = rsqrtf(var + 1e-5f);
                    #pragma unroll
                    for (int nt = 0; nt < 4; ++nt) {
                        int j = (nq << 6) + (nt << 4) + l15;
                        Ob[(size_t)u * Ee + j] = (acc2[mi][nt][r] - mu) * rstd * w2l[nt] + b2l[nt];
                    }
                }
            }
    }
}

extern "C" void kernel_launch(void* const* d_in, const int* in_sizes, int n_in,
                              void* d_out, int out_size, void* d_ws, size_t ws_size,
                              hipStream_t stream) {
    const float* Q    = (const float*)d_in[0];
    const float* K    = (const float*)d_in[1];
    const float* V    = (const float*)d_in[2];
    const float* M    = (const float*)d_in[3];
    const float* W1   = (const float*)d_in[4];
    const float* b1   = (const float*)d_in[5];
    const float* W2   = (const float*)d_in[6];
    const float* b2   = (const float*)d_in[7];
    const float* ln1w = (const float*)d_in[8];
    const float* ln1b = (const float*)d_in[9];
    const float* ln2w = (const float*)d_in[10];
    const float* ln2b = (const float*)d_in[11];
    float* out = (float*)d_out;

    int use_ws = (ws_size >= 262144) ? 1 : 0;
    const unsigned short* wsbf = (const unsigned short*)d_ws;
    if (use_ws) {
        convert_w_kernel<<<64, 256, 0, stream>>>(W1, W2, (unsigned short*)d_ws);
    }
    fusion_kernel<<<Bsz * Tt * Dd, 512, 0, stream>>>(Q, K, V, M, W1, b1, W2, b2,
                                                     ln1w, ln1b, ln2w, ln2b,
                                                     wsbf, use_ws, out);
}

// Round 3
// 588.854 us; speedup vs baseline: 1.0337x; 1.0337x over previous
//
#include <hip/hip_runtime.h>
#include <math.h>

#define Bsz 32
#define Tt  10
#define Dd  10
#define Uu  50
#define Pp  50
#define Ee  256

typedef __attribute__((ext_vector_type(8))) short bf16x8;   // MFMA A/B frag
typedef __attribute__((ext_vector_type(4))) float f32x4;    // MFMA C/D frag

#define STK 264   // sXbf / sH row stride (halfwords): 256+8, 16B-aligned rows
#define STV 72    // sVt row stride (16B-aligned rows)
#define STS 72    // sS row stride

// LDS regions (bytes). Big tensors sequentially alias region A (no sK anymore:
// K fragments are read directly from global/L2 during scores):
//  A [0,36864):      sVt (PV B, V^T) -> sXbf (post-LN1) -> sH (post-relu)
//  B [36864,46080):  sS (softmax P, bf16)
//  C [46080,48128):  red f32[64][2][2] (LN1) / red2 f32[64][4][2] (LN2)
// Total 48,128 B -> 3 blocks/CU (3*48,128 = 144,384 <= 163,840)
#define OFF_A 0
#define OFF_B 36864
#define OFF_C 46080
#define SMEM_TOT 48128

__device__ __forceinline__ unsigned short f2bf(float f) {      // RNE fp32->bf16
    unsigned u = __builtin_bit_cast(unsigned, f);
    u += 0x7fffu + ((u >> 16) & 1u);
    return (unsigned short)(u >> 16);
}
__device__ __forceinline__ float bf2f(unsigned short h) {
    unsigned u = ((unsigned)h) << 16;
    return __builtin_bit_cast(float, u);
}
// A/B fragment from LDS: lane q*16+l15 -> row r0+l15, cols c0+q*8..+7 (b128)
__device__ __forceinline__ bf16x8 ldfrag(const unsigned short* p, int stride, int r0, int c0, int lane) {
    return *(const bf16x8*)(p + (size_t)(r0 + (lane & 15)) * stride + c0 + ((lane >> 4) << 3));
}
// B fragment from global fp32 row-major [row][256] with row clamp (rows>=50 are
// masked downstream; clamp keeps loads in-bounds and values finite)
__device__ __forceinline__ bf16x8 kfrag(const float* __restrict__ Kb, int n, int k0, int lane) {
    int row = n + (lane & 15);
    row = row > 49 ? 49 : row;
    const int col = k0 + ((lane >> 4) << 3);
    const float4 a = *(const float4*)(Kb + (size_t)row * 256 + col);
    const float4 b = *(const float4*)(Kb + (size_t)row * 256 + col + 4);
    bf16x8 r;
    r[0] = (short)f2bf(a.x); r[1] = (short)f2bf(a.y); r[2] = (short)f2bf(a.z); r[3] = (short)f2bf(a.w);
    r[4] = (short)f2bf(b.x); r[5] = (short)f2bf(b.y); r[6] = (short)f2bf(b.z); r[7] = (short)f2bf(b.w);
    return r;
}
// W fragment straight from global (bf16 ws if available, else fp32 + convert)
__device__ __forceinline__ bf16x8 wfrag(const unsigned short* wbf, const float* wf, int use_ws,
                                        int n, int k0, int lane) {
    const int row = n + (lane & 15);
    const int col = k0 + ((lane >> 4) << 3);
    if (use_ws) {
        return *(const bf16x8*)(wbf + (size_t)row * 256 + col);
    }
    const float4 a = *(const float4*)(wf + (size_t)row * 256 + col);
    const float4 b = *(const float4*)(wf + (size_t)row * 256 + col + 4);
    bf16x8 r;
    r[0] = (short)f2bf(a.x); r[1] = (short)f2bf(a.y); r[2] = (short)f2bf(a.z); r[3] = (short)f2bf(a.w);
    r[4] = (short)f2bf(b.x); r[5] = (short)f2bf(b.y); r[6] = (short)f2bf(b.z); r[7] = (short)f2bf(b.w);
    return r;
}

__global__ void convert_w_kernel(const float* __restrict__ W1, const float* __restrict__ W2,
                                 unsigned short* __restrict__ ws) {
    int i4 = (blockIdx.x * 256 + threadIdx.x) * 4;
    float4 a = *(const float4*)(W1 + i4);
    ushort4 oa; oa.x = f2bf(a.x); oa.y = f2bf(a.y); oa.z = f2bf(a.z); oa.w = f2bf(a.w);
    *(ushort4*)(ws + i4) = oa;
    float4 b = *(const float4*)(W2 + i4);
    ushort4 ob; ob.x = f2bf(b.x); ob.y = f2bf(b.y); ob.z = f2bf(b.z); ob.w = f2bf(b.w);
    *(ushort4*)(ws + 65536 + i4) = ob;
}

__global__ __launch_bounds__(512, 4) void fusion_kernel(
    const float* __restrict__ Q,  const float* __restrict__ K,
    const float* __restrict__ V,  const float* __restrict__ Msk,
    const float* __restrict__ W1, const float* __restrict__ b1,
    const float* __restrict__ W2, const float* __restrict__ b2,
    const float* __restrict__ ln1w, const float* __restrict__ ln1b,
    const float* __restrict__ ln2w, const float* __restrict__ ln2b,
    const unsigned short* __restrict__ wsbf, int use_ws,
    float* __restrict__ out)
{
    __shared__ __align__(16) unsigned char smem[SMEM_TOT];
    unsigned short* sVt  = (unsigned short*)(smem + OFF_A);
    unsigned short* sXbf = (unsigned short*)(smem + OFF_A);   // after PV reads: sVt dead
    unsigned short* sH   = (unsigned short*)(smem + OFF_A);   // after FFN1 reads: sXbf dead
    unsigned short* sS   = (unsigned short*)(smem + OFF_B);
    float*          red  = (float*)(smem + OFF_C);   // [u][half][2] (LN1)
    float*          red2 = (float*)(smem + OFF_C);   // [u][nq][2]   (LN2; red dead)

    const int tid  = threadIdx.x;
    const int lane = tid & 63;
    const int wave = tid >> 6;
    const int quad = lane >> 4;
    const int l15  = lane & 15;

    // XCD-chunked swizzle: hw block h -> XCD h%8 (round-robin). Each XCD owns a
    // contiguous btd chunk of 400 so Q (d-neighbors) and K/V (t-neighbors) hit L2.
    const int btd = ((blockIdx.x & 7) * 400) + (blockIdx.x >> 3);
    const int b   = btd / (Tt * Dd);
    const int rem = btd % (Tt * Dd);
    const int t   = rem / Dd;
    const int d   = rem % Dd;

    const float* Qb = Q + ((size_t)(b * Tt + t) * Uu) * Ee;
    const float* Kb = K + ((size_t)(b * Dd + d) * Pp) * Ee;
    const float* Vb = V + ((size_t)(b * Dd + d) * Pp) * Ee;
    const float* Mb = Msk + ((size_t)((b * Tt + t) * Dd + d) * Uu) * Pp;
    float*       Ob = out + ((size_t)((b * Tt + t) * Dd + d) * Uu) * Ee;

    if (wave < 4) {
        // ---- Scores m-tile = wave: Q and K both direct from global/L2, softmax in regs ----
        const int mt = wave;
        int arow = mt * 16 + l15; if (arow > 49) arow = 49;   // clamp: garbage rows stay finite
        const float* qrow = Qb + (size_t)arow * Ee + (quad << 3);
        f32x4 acc[4];
        #pragma unroll
        for (int i = 0; i < 4; ++i) acc[i] = (f32x4){0.f, 0.f, 0.f, 0.f};
        #pragma unroll
        for (int k0 = 0; k0 < 256; k0 += 32) {
            float4 qa = *(const float4*)(qrow + k0);
            float4 qb = *(const float4*)(qrow + k0 + 4);
            bf16x8 a;
            a[0] = (short)f2bf(qa.x); a[1] = (short)f2bf(qa.y); a[2] = (short)f2bf(qa.z); a[3] = (short)f2bf(qa.w);
            a[4] = (short)f2bf(qb.x); a[5] = (short)f2bf(qb.y); a[6] = (short)f2bf(qb.z); a[7] = (short)f2bf(qb.w);
            #pragma unroll
            for (int nt = 0; nt < 4; ++nt) {
                bf16x8 bf = kfrag(Kb, nt << 4, k0, lane);
                acc[nt] = __builtin_amdgcn_mfma_f32_16x16x32_bf16(a, bf, acc[nt], 0, 0, 0);
            }
        }
        // logits: scale (sqrt(256)+1e-8 == 16.0f in fp32) + mask; p>=50 -> -inf-ish
        float l[4][4];
        #pragma unroll
        for (int nt = 0; nt < 4; ++nt) {
            int p = (nt << 4) + l15;
            #pragma unroll
            for (int r = 0; r < 4; ++r) {
                int u = mt * 16 + (quad << 2) + r;
                float v = acc[nt][r] * 0.0625f;
                if (p < Pp) { if (u < Uu) v += Mb[u * Pp + p]; }
                else v = -1e30f;
                l[nt][r] = v;
            }
        }
        #pragma unroll
        for (int r = 0; r < 4; ++r) {
            float m = fmaxf(fmaxf(l[0][r], l[1][r]), fmaxf(l[2][r], l[3][r]));
            #pragma unroll
            for (int msk = 1; msk < 16; msk <<= 1) m = fmaxf(m, __shfl_xor(m, msk));
            float e0 = __expf(l[0][r] - m), e1 = __expf(l[1][r] - m);
            float e2 = __expf(l[2][r] - m), e3 = __expf(l[3][r] - m);
            float s = e0 + e1 + e2 + e3;
            #pragma unroll
            for (int msk = 1; msk < 16; msk <<= 1) s += __shfl_xor(s, msk);
            float inv = 1.0f / s;
            int u = mt * 16 + (quad << 2) + r;
            sS[u * STS +  0 + l15] = f2bf(e0 * inv);
            sS[u * STS + 16 + l15] = f2bf(e1 * inv);
            sS[u * STS + 32 + l15] = f2bf(e2 * inv);
            sS[u * STS + 48 + l15] = f2bf(e3 * inv);
        }
    } else {
        // ---- Waves 4-7: stage V^T into region A, overlapped with scores ----
        const int lt = tid - 256;
        #pragma unroll 4
        for (int i = lt; i < 12800; i += 256) {
            int p = i >> 8, e = i & 255;
            sVt[e * STV + p] = f2bf(Vb[p * Ee + e]);
        }
        for (int i = lt; i < 3584; i += 256) {   // zero k-pad cols p=50..63
            int p = 50 + (i >> 8), e = i & 255;
            sVt[e * STV + p] = 0;
        }
    }
    __syncthreads();   // B1: sS + sVt ready

    // ---- PV: v_att = S.V (m-tile = w>>1, n-half = w&1) + Q residual + LN1 partials ----
    {
        const int mt = wave >> 1;
        const int nh = (wave & 1) << 7;
        f32x4 acc[8];
        #pragma unroll
        for (int i = 0; i < 8; ++i) acc[i] = (f32x4){0.f, 0.f, 0.f, 0.f};
        #pragma unroll
        for (int k0 = 0; k0 < 64; k0 += 32) {
            bf16x8 a = ldfrag(sS, STS, mt << 4, k0, lane);
            #pragma unroll
            for (int nt = 0; nt < 8; ++nt) {
                bf16x8 bf = ldfrag(sVt, STV, nh + (nt << 4), k0, lane);
                acc[nt] = __builtin_amdgcn_mfma_f32_16x16x32_bf16(a, bf, acc[nt], 0, 0, 0);
            }
        }
        float s1[4] = {0.f, 0.f, 0.f, 0.f}, s2[4] = {0.f, 0.f, 0.f, 0.f};
        #pragma unroll
        for (int nt = 0; nt < 8; ++nt) {
            int e = nh + (nt << 4) + l15;
            #pragma unroll
            for (int r = 0; r < 4; ++r) {
                int u = (mt << 4) + (quad << 2) + r;
                float x = 0.f;
                if (u < Uu) x = acc[nt][r] + Qb[(size_t)u * Ee + e];   // guard: no OOB Q read
                acc[nt][r] = x;
                s1[r] += x; s2[r] += x * x;
            }
        }
        #pragma unroll
        for (int msk = 1; msk < 16; msk <<= 1) {
            #pragma unroll
            for (int r = 0; r < 4; ++r) { s1[r] += __shfl_xor(s1[r], msk); s2[r] += __shfl_xor(s2[r], msk); }
        }
        if (l15 == 0) {
            #pragma unroll
            for (int r = 0; r < 4; ++r) {
                int u = (mt << 4) + (quad << 2) + r;
                red[u * 4 + (wave & 1) * 2 + 0] = s1[r];
                red[u * 4 + (wave & 1) * 2 + 1] = s2[r];
            }
        }
        __syncthreads();   // B2: red ready AND all PV reads of sVt done
        float mu[4], rstd[4];
        #pragma unroll
        for (int r = 0; r < 4; ++r) {
            int u = (mt << 4) + (quad << 2) + r;
            float sum = red[u * 4 + 0] + red[u * 4 + 2];
            float sq  = red[u * 4 + 1] + red[u * 4 + 3];
            mu[r] = sum * (1.0f / 256.0f);
            float var = sq * (1.0f / 256.0f) - mu[r] * mu[r];
            rstd[r] = rsqrtf(var + 1e-5f);
        }
        // write LN1 output into region A (sVt dead per B2)
        #pragma unroll
        for (int nt = 0; nt < 8; ++nt) {
            int e = nh + (nt << 4) + l15;
            float wv = ln1w[e], bv = ln1b[e];
            #pragma unroll
            for (int r = 0; r < 4; ++r) {
                int u = (mt << 4) + (quad << 2) + r;
                float o = (u < Uu) ? ((acc[nt][r] - mu[r]) * rstd[r] * wv + bv) : 0.f;
                sXbf[u * STK + e] = f2bf(o);
            }
        }
    }
    __syncthreads();   // B3: sXbf ready

    // ---- FFN1: H = relu(X.W1^T + b1); wave = (m-pair, n-quarter); W frags direct from L2 ----
    const int mp = wave >> 2;     // m-tiles {2mp, 2mp+1}
    const int nq = wave & 3;      // n-tiles 4nq..4nq+3
    unsigned resid[2][4][2];      // residual X at this wave's FFN2 output coords (packed bf16 pairs)
    {
        f32x4 acc2[2][4];
        #pragma unroll
        for (int mi = 0; mi < 2; ++mi)
            #pragma unroll
            for (int nt = 0; nt < 4; ++nt) acc2[mi][nt] = (f32x4){0.f, 0.f, 0.f, 0.f};
        float b1v[4];
        #pragma unroll
        for (int nt = 0; nt < 4; ++nt) b1v[nt] = b1[(nq << 6) + (nt << 4) + l15];
        #pragma unroll
        for (int k0 = 0; k0 < 256; k0 += 32) {
            bf16x8 a0 = ldfrag(sXbf, STK, (mp << 5),      k0, lane);
            bf16x8 a1 = ldfrag(sXbf, STK, (mp << 5) + 16, k0, lane);
            #pragma unroll
            for (int nt = 0; nt < 4; ++nt) {
                bf16x8 bf = wfrag(wsbf, W1, use_ws, (nq << 6) + (nt << 4), k0, lane);
                acc2[0][nt] = __builtin_amdgcn_mfma_f32_16x16x32_bf16(a0, bf, acc2[0][nt], 0, 0, 0);
                acc2[1][nt] = __builtin_amdgcn_mfma_f32_16x16x32_bf16(a1, bf, acc2[1][nt], 0, 0, 0);
            }
        }
        // capture residual X (32 bf16 -> 16 packed VGPRs) BEFORE sH overwrites region A
        #pragma unroll
        for (int mi = 0; mi < 2; ++mi)
            #pragma unroll
            for (int nt = 0; nt < 4; ++nt) {
                int j = (nq << 6) + (nt << 4) + l15;
                #pragma unroll
                for (int rp = 0; rp < 2; ++rp) {
                    int u0 = (mp << 5) + (mi << 4) + (quad << 2) + rp * 2;
                    unsigned lo = sXbf[(size_t)u0 * STK + j];
                    unsigned hi = sXbf[(size_t)(u0 + 1) * STK + j];
                    resid[mi][nt][rp] = lo | (hi << 16);
                }
            }
        __syncthreads();   // B4: all sXbf reads (A-frags + residual) done
        #pragma unroll
        for (int mi = 0; mi < 2; ++mi)
            #pragma unroll
            for (int nt = 0; nt < 4; ++nt) {
                int j = (nq << 6) + (nt << 4) + l15;
                #pragma unroll
                for (int r = 0; r < 4; ++r) {
                    int u = (mp << 5) + (mi << 4) + (quad << 2) + r;
                    sH[u * STK + j] = f2bf(fmaxf(acc2[mi][nt][r] + b1v[nt], 0.f));
                }
            }
    }
    __syncthreads();   // B5: sH ready

    // ---- FFN2: Y = H.W2^T + b2 + X(regs); LN2; store ----
    {
        f32x4 acc2[2][4];
        #pragma unroll
        for (int mi = 0; mi < 2; ++mi)
            #pragma unroll
            for (int nt = 0; nt < 4; ++nt) acc2[mi][nt] = (f32x4){0.f, 0.f, 0.f, 0.f};
        float b2v[4], w2l[4], b2l[4];
        #pragma unroll
        for (int nt = 0; nt < 4; ++nt) {
            int j = (nq << 6) + (nt << 4) + l15;
            b2v[nt] = b2[j]; w2l[nt] = ln2w[j]; b2l[nt] = ln2b[j];
        }
        #pragma unroll
        for (int k0 = 0; k0 < 256; k0 += 32) {
            bf16x8 a0 = ldfrag(sH, STK, (mp << 5),      k0, lane);
            bf16x8 a1 = ldfrag(sH, STK, (mp << 5) + 16, k0, lane);
            #pragma unroll
            for (int nt = 0; nt < 4; ++nt) {
                bf16x8 bf = wfrag(wsbf + 65536, W2, use_ws, (nq << 6) + (nt << 4), k0, lane);
                acc2[0][nt] = __builtin_amdgcn_mfma_f32_16x16x32_bf16(a0, bf, acc2[0][nt], 0, 0, 0);
                acc2[1][nt] = __builtin_amdgcn_mfma_f32_16x16x32_bf16(a1, bf, acc2[1][nt], 0, 0, 0);
            }
        }
        // y = ffn2 + b2 + residual X(regs); per-row partial sums over this wave's 64 cols
        float s1[2][4], s2[2][4];
        #pragma unroll
        for (int mi = 0; mi < 2; ++mi)
            #pragma unroll
            for (int r = 0; r < 4; ++r) { s1[mi][r] = 0.f; s2[mi][r] = 0.f; }
        #pragma unroll
        for (int mi = 0; mi < 2; ++mi)
            #pragma unroll
            for (int nt = 0; nt < 4; ++nt) {
                #pragma unroll
                for (int r = 0; r < 4; ++r) {
                    unsigned pk = resid[mi][nt][r >> 1];
                    unsigned short rb = (r & 1) ? (unsigned short)(pk >> 16) : (unsigned short)(pk & 0xffffu);
                    float y = acc2[mi][nt][r] + b2v[nt] + bf2f(rb);
                    acc2[mi][nt][r] = y;
                    s1[mi][r] += y; s2[mi][r] += y * y;
                }
            }
        #pragma unroll
        for (int msk = 1; msk < 16; msk <<= 1)
            #pragma unroll
            for (int mi = 0; mi < 2; ++mi)
                #pragma unroll
                for (int r = 0; r < 4; ++r) {
                    s1[mi][r] += __shfl_xor(s1[mi][r], msk);
                    s2[mi][r] += __shfl_xor(s2[mi][r], msk);
                }
        if (l15 == 0) {
            #pragma unroll
            for (int mi = 0; mi < 2; ++mi)
                #pragma unroll
                for (int r = 0; r < 4; ++r) {
                    int u = (mp << 5) + (mi << 4) + (quad << 2) + r;
                    red2[u * 8 + nq * 2 + 0] = s1[mi][r];
                    red2[u * 8 + nq * 2 + 1] = s2[mi][r];
                }
        }
        __syncthreads();   // B6: red2 ready
        #pragma unroll
        for (int mi = 0; mi < 2; ++mi)
            #pragma unroll
            for (int r = 0; r < 4; ++r) {
                int u = (mp << 5) + (mi << 4) + (quad << 2) + r;
                if (u < Uu) {
                    float sum = red2[u * 8 + 0] + red2[u * 8 + 2] + red2[u * 8 + 4] + red2[u * 8 + 6];
                    float sq  = red2[u * 8 + 1] + red2[u * 8 + 3] + red2[u * 8 + 5] + red2[u * 8 + 7];
                    float mu = sum * (1.0f / 256.0f);
                    float var = sq * (1.0f / 256.0f) - mu * mu;
                    float rstd = rsqrtf(var + 1e-5f);
                    #pragma unroll
                    for (int nt = 0; nt < 4; ++nt) {
                        int j = (nq << 6) + (nt << 4) + l15;
                        Ob[(size_t)u * Ee + j] = (acc2[mi][nt][r] - mu) * rstd * w2l[nt] + b2l[nt];
                    }
                }
            }
    }
}

extern "C" void kernel_launch(void* const* d_in, const int* in_sizes, int n_in,
                              void* d_out, int out_size, void* d_ws, size_t ws_size,
                              hipStream_t stream) {
    const float* Q    = (const float*)d_in[0];
    const float* K    = (const float*)d_in[1];
    const float* V    = (const float*)d_in[2];
    const float* M    = (const float*)d_in[3];
    const float* W1   = (const float*)d_in[4];
    const float* b1   = (const float*)d_in[5];
    const float* W2   = (const float*)d_in[6];
    const float* b2   = (const float*)d_in[7];
    const float* ln1w = (const float*)d_in[8];
    const float* ln1b = (const float*)d_in[9];
    const float* ln2w = (const float*)d_in[10];
    const float* ln2b = (const float*)d_in[11];
    float* out = (float*)d_out;

    int use_ws = (ws_size >= 262144) ? 1 : 0;
    const unsigned short* wsbf = (const unsigned short*)d_ws;
    if (use_ws) {
        convert_w_kernel<<<64, 256, 0, stream>>>(W1, W2, (unsigned short*)d_ws);
    }
    fusion_kernel<<<Bsz * Tt * Dd, 512, 0, stream>>>(Q, K, V, M, W1, b1, W2, b2,
                                                     ln1w, ln1b, ln2w, ln2b,
                                                     wsbf, use_ws, out);
}